// Round 2
// baseline (16622.780 us; speedup 1.0000x reference)
//
#include <hip/hip_runtime.h>
#include <hip/hip_bf16.h>

// BiLSTM, B=128 S=1024 D=128 H=256, transpose quirk: u_t[b][k] = x[k,t,b].
// Round 2: inputs/outputs are FP32 (round-1 NaN == fp32 misread as bf16 pairs).
// Compute in bf16 MFMA (threshold 2.6e-2 permits), fp32 state/bias/epilogue.
//
// Persistent kernel, 32 WGs (2 dir x 2 b-half x 8 h-slice), 256 thr.
// W slice (4g x 32h x 384k bf16, rows padded to 392) resident in LDS.
// Per step: stage u_t + h_prev into LDS concat[64b][392], MFMA 16x16x32 bf16
// (M=128=4g*32h, N=64, K=384), activations in C-fragment layout, c in regs.
// h exchanged as packed bf16 via agent-scope u32 atomics in d_ws, double-
// buffered by step parity; flag barrier = per-step counters (8 WGs/group).

typedef unsigned int  u32;
typedef unsigned short u16;
typedef short short4_t __attribute__((ext_vector_type(4)));
typedef short short8_t __attribute__((ext_vector_type(8)));
typedef float float4_t __attribute__((ext_vector_type(4)));
typedef float float2_t __attribute__((ext_vector_type(2)));

#define S_LEN 1024
#define D_IN  128
#define H_DIM 256
#define B_DIM 128
#define K_DIM 384
#define LSTR  392                       // K_DIM + 8 pad
#define SMEM_BYTES ((128 + 64) * LSTR * 2)   // 150528 B

__device__ __forceinline__ u16 f2bf(float f) {
    union { float f; u32 u; } v; v.f = f;
    u32 r = v.u + 0x7fffu + ((v.u >> 16) & 1u);
    return (u16)(r >> 16);
}
__device__ __forceinline__ float sig_f(float x) {
    return __builtin_amdgcn_rcpf(1.f + __expf(-x));
}
__device__ __forceinline__ float tanh_f(float x) {
    return 2.f * sig_f(2.f * x) - 1.f;
}

__global__ __launch_bounds__(256, 1)
void bilstm_kernel(const float* __restrict__ x,
                   const float* __restrict__ Wf, const float* __restrict__ bf_,
                   const float* __restrict__ Wb, const float* __restrict__ bb_,
                   float* __restrict__ out,
                   u32* __restrict__ cnt,     // [2 dir][2 bg][1024] (memset 0)
                   u16* __restrict__ hbuf)    // [2 dir][2 par][128 b][256 h] bf16
{
    extern __shared__ char smem[];
    u16* Wl = (u16*)smem;                 // [128][LSTR]
    u16* Cc = (u16*)smem + 128 * LSTR;    // [64][LSTR]

    const int tid = threadIdx.x;
    const int bx  = blockIdx.x;
    const int dir = bx >> 4;              // 0 fwd, 1 bwd
    const int id  = bx & 15;
    const int bg  = id >> 3;              // b-half
    const int hs  = id & 7;               // h-slice
    const int b0  = bg * 64;
    const int h0  = hs * 32;

    const float* W    = dir ? Wb : Wf;
    const float* bias = dir ? bb_ : bf_;

    // ---- load W slice into LDS (fp32 -> bf16): row m=g*32+hl <- W[g][h0+hl][k]
    for (int it = 0; it < 48; ++it) {
        int v  = tid + it * 256;          // 0..12287 (128 rows * 96 vec4)
        int r  = v / 96;
        int kv = v - r * 96;
        int g  = r >> 5, hl = r & 31;
        const float4_t src = *(const float4_t*)(W + ((g * H_DIM + h0 + hl) * K_DIM + kv * 4));
        short4_t d;
        d[0] = (short)f2bf(src[0]); d[1] = (short)f2bf(src[1]);
        d[2] = (short)f2bf(src[2]); d[3] = (short)f2bf(src[3]);
        *(short4_t*)(Wl + r * LSTR + kv * 4) = d;
    }

    const int lane = tid & 63;
    const int wid  = tid >> 6;            // 4 waves
    const int quad = lane >> 4;
    const int l15  = lane & 15;
    const int hlt  = wid >> 1;            // m-half (16 h rows each)
    const int nh   = wid & 1;             // n-half (32 b cols each)

    float bias_r[4][4];
    for (int g = 0; g < 4; ++g)
        for (int i = 0; i < 4; ++i)
            bias_r[g][i] = bias[g * H_DIM + h0 + hlt * 16 + quad * 4 + i];

    float c_st[2][4];
    for (int nt = 0; nt < 2; ++nt)
        for (int i = 0; i < 4; ++i) c_st[nt][i] = 0.f;

    u32* mycnt = cnt + (dir * 2 + bg) * S_LEN;

    __syncthreads();                       // W slice visible to all waves

    for (int s = 0; s < S_LEN; ++s) {
        const int t = dir ? (S_LEN - 1 - s) : s;

        // ---- stage u_t (fp32 -> bf16); independent of h, overlaps spin ----
        {
            const int m  = tid & 31;       // b-pair
            const int kb = tid >> 5;       // 0..7
            const float* xcol = x + (size_t)t * D_IN + b0 + 2 * m;
            for (int it = 0; it < 16; ++it) {
                int k = it * 8 + kb;
                float2_t v = *(const float2_t*)(xcol + (size_t)k * (S_LEN * D_IN));
                Cc[(2 * m) * LSTR + k]     = f2bf(v[0]);
                Cc[(2 * m + 1) * LSTR + k] = f2bf(v[1]);
            }
        }
        if (s > 0 && tid == 0) {
            while (__hip_atomic_load(&mycnt[s - 1], __ATOMIC_ACQUIRE,
                                     __HIP_MEMORY_SCOPE_AGENT) < 8u)
                __builtin_amdgcn_s_sleep(1);
        }
        __syncthreads();

        // ---- stage h_prev (bf16-packed, agent-scope) ----
        if (s == 0) {
            for (int it = 0; it < 32; ++it) {
                int f = tid + it * 256;
                int b = f >> 7, jj = f & 127;
                *(u32*)(Cc + b * LSTR + D_IN + 2 * jj) = 0u;
            }
        } else {
            const int par_r = (s - 1) & 1;
            u16* hsrc = hbuf + ((dir * 2 + par_r) * B_DIM) * H_DIM;
            for (int it = 0; it < 32; ++it) {
                int f = tid + it * 256;
                int b = f >> 7, jj = f & 127;
                u32 v = __hip_atomic_load((u32*)(hsrc + (b0 + b) * H_DIM + 2 * jj),
                                          __ATOMIC_RELAXED, __HIP_MEMORY_SCOPE_AGENT);
                *(u32*)(Cc + b * LSTR + D_IN + 2 * jj) = v;
            }
        }
        __syncthreads();

        // ---- GEMM: z[4g x 32h, 64b] = W_slice @ concat^T ----
        float4_t acc[4][2];
        for (int g = 0; g < 4; ++g)
            for (int nt = 0; nt < 2; ++nt)
                acc[g][nt] = (float4_t){0.f, 0.f, 0.f, 0.f};

        #pragma unroll
        for (int ks = 0; ks < 12; ++ks) {
            const int ko = ks * 32 + quad * 8;
            short8_t a[4], bb[2];
            for (int g = 0; g < 4; ++g)
                a[g] = *(const short8_t*)(Wl + (g * 32 + hlt * 16 + l15) * LSTR + ko);
            for (int nt = 0; nt < 2; ++nt)
                bb[nt] = *(const short8_t*)(Cc + (nh * 32 + nt * 16 + l15) * LSTR + ko);
            for (int g = 0; g < 4; ++g)
                for (int nt = 0; nt < 2; ++nt)
                    acc[g][nt] = __builtin_amdgcn_mfma_f32_16x16x32_bf16(
                        a[g], bb[nt], acc[g][nt], 0, 0, 0);
        }

        // ---- activations + state update + outputs (fp32 epilogue) ----
        const int par_w = s & 1;
        u16* hdst = hbuf + ((dir * 2 + par_w) * B_DIM) * H_DIM;
        const int hrow = h0 + hlt * 16 + quad * 4;   // this thread's 4 h rows

        for (int nt = 0; nt < 2; ++nt) {
            const int b = b0 + nh * 32 + nt * 16 + l15;
            float hv[4], cv[4];
            for (int i = 0; i < 4; ++i) {
                float zf = acc[0][nt][i] + bias_r[0][i];
                float zi = acc[1][nt][i] + bias_r[1][i];
                float zc = acc[2][nt][i] + bias_r[2][i];
                float zo = acc[3][nt][i] + bias_r[3][i];
                float fg = sig_f(zf);
                float ig = sig_f(zi);
                float og = sig_f(zo);
                float ct = tanh_f(zc);
                float c  = fg * c_st[nt][i] + ig * ct;
                c_st[nt][i] = c;
                float h  = og * tanh_f(c);
                hv[i] = h; cv[i] = c;
            }
            // h broadcast buffer (packed bf16, device-visible)
            u32 u0 = (u32)f2bf(hv[0]) | ((u32)f2bf(hv[1]) << 16);
            u32 u1 = (u32)f2bf(hv[2]) | ((u32)f2bf(hv[3]) << 16);
            __hip_atomic_store((u32*)(hdst + b * H_DIM + hrow), u0,
                               __ATOMIC_RELAXED, __HIP_MEMORY_SCOPE_AGENT);
            __hip_atomic_store((u32*)(hdst + b * H_DIM + hrow + 2), u1,
                               __ATOMIC_RELAXED, __HIP_MEMORY_SCOPE_AGENT);
            // output[b][t][dir*256 + h] in fp32
            float4_t ho; ho[0]=hv[0]; ho[1]=hv[1]; ho[2]=hv[2]; ho[3]=hv[3];
            *(float4_t*)(out + ((size_t)b * (S_LEN * 2 * H_DIM)
                          + (size_t)t * (2 * H_DIM) + dir * H_DIM + hrow)) = ho;
            if (s == S_LEN - 1) {  // final states (h then c), fp32
                size_t fo = (size_t)67108864 + (size_t)dir * 32768
                          + (size_t)b * H_DIM + hrow;
                *(float4_t*)(out + fo) = ho;
                float4_t co; co[0]=cv[0]; co[1]=cv[1]; co[2]=cv[2]; co[3]=cv[3];
                *(float4_t*)(out + fo + 65536) = co;
            }
        }
        __syncthreads();   // all h stores drained (vmcnt0) before flag
        if (tid == 0)
            __hip_atomic_fetch_add(&mycnt[s], 1u, __ATOMIC_RELEASE,
                                   __HIP_MEMORY_SCOPE_AGENT);
    }
}

extern "C" void kernel_launch(void* const* d_in, const int* in_sizes, int n_in,
                              void* d_out, int out_size, void* d_ws, size_t ws_size,
                              hipStream_t stream) {
    (void)in_sizes; (void)n_in; (void)out_size; (void)ws_size;
    hipFuncSetAttribute((const void*)bilstm_kernel,
                        hipFuncAttributeMaxDynamicSharedMemorySize, SMEM_BYTES);
    u32* cnt  = (u32*)d_ws;                         // 16 KB counters
    u16* hbuf = (u16*)((char*)d_ws + 16384);        // 256 KB h double-buffer
    hipMemsetAsync(d_ws, 0, 16384, stream);         // counters start at 0
    bilstm_kernel<<<dim3(32), dim3(256), SMEM_BYTES, stream>>>(
        (const float*)d_in[0], (const float*)d_in[1], (const float*)d_in[2],
        (const float*)d_in[3], (const float*)d_in[4],
        (float*)d_out, cnt, hbuf);
}

// Round 3
// 7545.809 us; speedup vs baseline: 2.2029x; 2.2029x over previous
//
#include <hip/hip_runtime.h>
#include <hip/hip_bf16.h>

// BiLSTM, B=128 S=1024 D=128 H=256, transpose quirk: u_t[r][k] = x[k,t,r].
// Round 3: round 2 passed (16.6 ms) but ACQUIRE-spin emitted buffer_inv sc1
// per poll + RELEASE emitted buffer_wbl2 -> full L2 nuke every step (FETCH
// 1 GB = 32 WG x 32 MB, zero reuse). Fix: all flag/h atomics RELAXED agent
// scope (per-access L2 bypass only, no cache-wide maintenance); ordering via
// __syncthreads' vmcnt(0) drain. Also: one-time x transpose->bf16 pre-pass
// (kills 8-way ds_write_b16 conflicts, staging becomes 16B loads + b128
// writes), h exchange widened to u64 atomics.

typedef unsigned int  u32;
typedef unsigned long long u64;
typedef unsigned short u16;
typedef short short4_t __attribute__((ext_vector_type(4)));
typedef short short8_t __attribute__((ext_vector_type(8)));
typedef float float4_t __attribute__((ext_vector_type(4)));
typedef float float2_t __attribute__((ext_vector_type(2)));

#define S_LEN 1024
#define D_IN  128
#define H_DIM 256
#define B_DIM 128
#define K_DIM 384
#define LSTR  392                       // K_DIM + 8 pad (784 B rows, 16B-aligned)
#define SMEM_BYTES ((128 + 64) * LSTR * 2)   // 150528 B

// d_ws layout
#define WS_CNT   0                      // 16 KB counters
#define WS_HBUF  16384                  // 256 KB h double-buffer (bf16)
#define WS_XBT   278528                 // 32 MB xbt[t][r][k] bf16
#define WS_NEED  (WS_XBT + (size_t)S_LEN * B_DIM * D_IN * 2)

__device__ __forceinline__ u16 f2bf(float f) {
    union { float f; u32 u; } v; v.f = f;
    u32 r = v.u + 0x7fffu + ((v.u >> 16) & 1u);
    return (u16)(r >> 16);
}
__device__ __forceinline__ float sig_f(float x) {
    return __builtin_amdgcn_rcpf(1.f + __expf(-x));
}
__device__ __forceinline__ float tanh_f(float x) {
    return 2.f * sig_f(2.f * x) - 1.f;
}

// ---- pre-pass: xbt[t][r][k] = bf16(x[k][t][r]) ; one WG per t ----
__global__ __launch_bounds__(256, 4)
void tx_kernel(const float* __restrict__ x, u16* __restrict__ xbt)
{
    __shared__ u16 tile[128][136];      // 272 B rows (16B-aligned)
    const int t   = blockIdx.x;
    const int tid = threadIdx.x;
    for (int c = 0; c < 16; ++c) {
        int f = tid + c * 256;          // 0..4095
        int k = f >> 5, q = f & 31;     // k row, r-chunk
        float4_t v = *(const float4_t*)(x + (size_t)k * (S_LEN * D_IN)
                                          + (size_t)t * D_IN + 4 * q);
        tile[4 * q + 0][k] = f2bf(v[0]);
        tile[4 * q + 1][k] = f2bf(v[1]);
        tile[4 * q + 2][k] = f2bf(v[2]);
        tile[4 * q + 3][k] = f2bf(v[3]);
    }
    __syncthreads();
    u16* dst = xbt + (size_t)t * (B_DIM * D_IN);
    for (int c = 0; c < 8; ++c) {
        int f = tid + c * 256;          // 0..2047
        int r = f >> 4, kc = f & 15;
        *(short8_t*)(dst + r * D_IN + kc * 8) = *(const short8_t*)(&tile[r][kc * 8]);
    }
}

__global__ __launch_bounds__(256, 1)
void bilstm_kernel(const float* __restrict__ x,
                   const float* __restrict__ Wf, const float* __restrict__ bf_,
                   const float* __restrict__ Wb, const float* __restrict__ bb_,
                   float* __restrict__ out,
                   u32* __restrict__ cnt,     // [2 dir][2 bg][1024] (memset 0)
                   u16* __restrict__ hbuf,    // [2 dir][2 par][128 r][256 h] bf16
                   const u16* __restrict__ xbt,
                   int use_xbt)
{
    extern __shared__ char smem[];
    u16* Wl = (u16*)smem;                 // [128][LSTR]
    u16* Cc = (u16*)smem + 128 * LSTR;    // [64][LSTR]

    const int tid = threadIdx.x;
    const int bx  = blockIdx.x;
    const int dir = bx >> 4;              // 0 fwd, 1 bwd
    const int id  = bx & 15;
    const int bg  = id >> 3;              // r-half
    const int hs  = id & 7;               // h-slice
    const int b0  = bg * 64;
    const int h0  = hs * 32;

    const float* W    = dir ? Wb : Wf;
    const float* bias = dir ? bb_ : bf_;

    // ---- load W slice into LDS (fp32 -> bf16): row m=g*32+hl <- W[g][h0+hl][k]
    for (int it = 0; it < 48; ++it) {
        int v  = tid + it * 256;          // 0..12287 (128 rows * 96 vec4)
        int r  = v / 96;
        int kv = v - r * 96;
        int g  = r >> 5, hl = r & 31;
        const float4_t src = *(const float4_t*)(W + ((g * H_DIM + h0 + hl) * K_DIM + kv * 4));
        short4_t d;
        d[0] = (short)f2bf(src[0]); d[1] = (short)f2bf(src[1]);
        d[2] = (short)f2bf(src[2]); d[3] = (short)f2bf(src[3]);
        *(short4_t*)(Wl + r * LSTR + kv * 4) = d;
    }

    const int lane = tid & 63;
    const int wid  = tid >> 6;            // 4 waves
    const int quad = lane >> 4;
    const int l15  = lane & 15;
    const int hlt  = wid >> 1;            // m-half (16 h rows each)
    const int nh   = wid & 1;             // n-half (32 b cols each)

    float bias_r[4][4];
    for (int g = 0; g < 4; ++g)
        for (int i = 0; i < 4; ++i)
            bias_r[g][i] = bias[g * H_DIM + h0 + hlt * 16 + quad * 4 + i];

    float c_st[2][4];
    for (int nt = 0; nt < 2; ++nt)
        for (int i = 0; i < 4; ++i) c_st[nt][i] = 0.f;

    u32* mycnt = cnt + (dir * 2 + bg) * S_LEN;

    __syncthreads();                       // W slice visible to all waves

    for (int s = 0; s < S_LEN; ++s) {
        const int t = dir ? (S_LEN - 1 - s) : s;

        // ---- stage u_t (independent of h; overlaps the spin below) ----
        if (use_xbt) {
            const u16* xs = xbt + (size_t)t * (B_DIM * D_IN) + b0 * D_IN;
            #pragma unroll
            for (int it = 0; it < 4; ++it) {
                int f = tid + it * 256;   // 0..1023 (64 rows * 16 chunks)
                int r = f >> 4, kc = f & 15;
                short8_t v = *(const short8_t*)(xs + r * D_IN + kc * 8);
                *(short8_t*)(Cc + r * LSTR + kc * 8) = v;
            }
        } else {
            const int m  = tid & 31;
            const int kb = tid >> 5;
            const float* xcol = x + (size_t)t * D_IN + b0 + 2 * m;
            for (int it = 0; it < 16; ++it) {
                int k = it * 8 + kb;
                float2_t v = *(const float2_t*)(xcol + (size_t)k * (S_LEN * D_IN));
                Cc[(2 * m) * LSTR + k]     = f2bf(v[0]);
                Cc[(2 * m + 1) * LSTR + k] = f2bf(v[1]);
            }
        }
        if (s > 0 && tid == 0) {
            // RELAXED spin: agent-scope load bypasses L2 per-access; no buffer_inv
            while (__hip_atomic_load(&mycnt[s - 1], __ATOMIC_RELAXED,
                                     __HIP_MEMORY_SCOPE_AGENT) < 8u)
                __builtin_amdgcn_s_sleep(1);
        }
        __syncthreads();

        // ---- stage h_prev (bf16-packed u64, agent-scope relaxed) ----
        if (s == 0) {
            for (int it = 0; it < 16; ++it) {
                int f = tid + it * 256;
                int r = f >> 6, jj = f & 63;
                *(u64*)(Cc + r * LSTR + D_IN + 4 * jj) = 0ull;
            }
        } else {
            const int par_r = (s - 1) & 1;
            const u16* hsrc = hbuf + ((dir * 2 + par_r) * B_DIM) * H_DIM;
            #pragma unroll 4
            for (int it = 0; it < 16; ++it) {
                int f = tid + it * 256;   // 0..4095 (64 rows * 64 u64-chunks)
                int r = f >> 6, jj = f & 63;
                u64 v = __hip_atomic_load((const u64*)(hsrc + (b0 + r) * H_DIM + 4 * jj),
                                          __ATOMIC_RELAXED, __HIP_MEMORY_SCOPE_AGENT);
                *(u64*)(Cc + r * LSTR + D_IN + 4 * jj) = v;
            }
        }
        __syncthreads();

        // ---- GEMM: z[4g x 32h, 64b] = W_slice @ concat^T ----
        float4_t acc[4][2];
        for (int g = 0; g < 4; ++g)
            for (int nt = 0; nt < 2; ++nt)
                acc[g][nt] = (float4_t){0.f, 0.f, 0.f, 0.f};

        #pragma unroll
        for (int ks = 0; ks < 12; ++ks) {
            const int ko = ks * 32 + quad * 8;
            short8_t a[4], bb[2];
            for (int g = 0; g < 4; ++g)
                a[g] = *(const short8_t*)(Wl + (g * 32 + hlt * 16 + l15) * LSTR + ko);
            for (int nt = 0; nt < 2; ++nt)
                bb[nt] = *(const short8_t*)(Cc + (nh * 32 + nt * 16 + l15) * LSTR + ko);
            for (int g = 0; g < 4; ++g)
                for (int nt = 0; nt < 2; ++nt)
                    acc[g][nt] = __builtin_amdgcn_mfma_f32_16x16x32_bf16(
                        a[g], bb[nt], acc[g][nt], 0, 0, 0);
        }

        // ---- activations + state update + outputs (fp32 epilogue) ----
        const int par_w = s & 1;
        u16* hdst = hbuf + ((dir * 2 + par_w) * B_DIM) * H_DIM;
        const int hrow = h0 + hlt * 16 + quad * 4;   // this thread's 4 h rows

        for (int nt = 0; nt < 2; ++nt) {
            const int b = b0 + nh * 32 + nt * 16 + l15;
            float hv[4], cv[4];
            for (int i = 0; i < 4; ++i) {
                float zf = acc[0][nt][i] + bias_r[0][i];
                float zi = acc[1][nt][i] + bias_r[1][i];
                float zc = acc[2][nt][i] + bias_r[2][i];
                float zo = acc[3][nt][i] + bias_r[3][i];
                float fg = sig_f(zf);
                float ig = sig_f(zi);
                float og = sig_f(zo);
                float ct = tanh_f(zc);
                float c  = fg * c_st[nt][i] + ig * ct;
                c_st[nt][i] = c;
                float h  = og * tanh_f(c);
                hv[i] = h; cv[i] = c;
            }
            // h broadcast (packed bf16 u64, agent-scope relaxed)
            u64 hp = (u64)f2bf(hv[0]) | ((u64)f2bf(hv[1]) << 16)
                   | ((u64)f2bf(hv[2]) << 32) | ((u64)f2bf(hv[3]) << 48);
            __hip_atomic_store((u64*)(hdst + b * H_DIM + hrow), hp,
                               __ATOMIC_RELAXED, __HIP_MEMORY_SCOPE_AGENT);
            // output[b][t][dir*256 + h] in fp32
            float4_t ho; ho[0]=hv[0]; ho[1]=hv[1]; ho[2]=hv[2]; ho[3]=hv[3];
            *(float4_t*)(out + ((size_t)b * (S_LEN * 2 * H_DIM)
                          + (size_t)t * (2 * H_DIM) + dir * H_DIM + hrow)) = ho;
            if (s == S_LEN - 1) {  // final states (h then c), fp32
                size_t fo = (size_t)67108864 + (size_t)dir * 32768
                          + (size_t)b * H_DIM + hrow;
                *(float4_t*)(out + fo) = ho;
                float4_t co; co[0]=cv[0]; co[1]=cv[1]; co[2]=cv[2]; co[3]=cv[3];
                *(float4_t*)(out + fo + 65536) = co;
            }
        }
        __syncthreads();   // vmcnt(0) drain: h stores globally visible
        if (tid == 0)
            __hip_atomic_fetch_add(&mycnt[s], 1u, __ATOMIC_RELAXED,
                                   __HIP_MEMORY_SCOPE_AGENT);
    }
}

extern "C" void kernel_launch(void* const* d_in, const int* in_sizes, int n_in,
                              void* d_out, int out_size, void* d_ws, size_t ws_size,
                              hipStream_t stream) {
    (void)in_sizes; (void)n_in; (void)out_size;
    hipFuncSetAttribute((const void*)bilstm_kernel,
                        hipFuncAttributeMaxDynamicSharedMemorySize, SMEM_BYTES);
    u32* cnt  = (u32*)d_ws;
    u16* hbuf = (u16*)((char*)d_ws + WS_HBUF);
    u16* xbt  = (u16*)((char*)d_ws + WS_XBT);
    const int use_xbt = (ws_size >= WS_NEED) ? 1 : 0;
    hipMemsetAsync(d_ws, 0, 16384, stream);         // counters start at 0
    if (use_xbt)
        tx_kernel<<<dim3(S_LEN), dim3(256), 0, stream>>>((const float*)d_in[0], xbt);
    bilstm_kernel<<<dim3(32), dim3(256), SMEM_BYTES, stream>>>(
        (const float*)d_in[0], (const float*)d_in[1], (const float*)d_in[2],
        (const float*)d_in[3], (const float*)d_in[4],
        (float*)d_out, cnt, hbuf, xbt, use_xbt);
}